// Round 13
// baseline (207.404 us; speedup 1.0000x reference)
//
#include <hip/hip_runtime.h>

#define N_NODES 100000
#define N_EDGES 1200000
#define N_GRAPHS 256
#define IN_C 5
#define HID_C 64
#define OUT_C 2

#define BSH 7
#define BNODES 128
#define NB ((N_NODES + BNODES - 1) / BNODES)        // 782
#define CAPB 2048                                   // fixed bucket capacity (E=1534, sigma=39)
#define EPB 16384                                   // edges per block (binning; 84B runs/bucket)
#define NBLK_E ((N_EDGES + EPB - 1) / EPB)          // 74
#define GNPW 8                                      // nodes per wave in fused gather2+pool
#define L1NPW 8                                     // nodes per wave in k_l1

typedef unsigned int uint32;

// fp32 -> bf16 round-to-nearest-even (returns 16-bit pattern)
__device__ __forceinline__ uint32 f2bf(float f) {
    uint32 x = __float_as_uint(f);
    return (x + 0x7FFFu + ((x >> 16) & 1u)) >> 16;
}
__device__ __forceinline__ float bflo(uint32 r) { return __uint_as_float(r << 16); }
__device__ __forceinline__ float bfhi(uint32 r) { return __uint_as_float(r & 0xFFFF0000u); }

// ---- bin edges into fixed-capacity bucket regions, packed (dst_local<<17)|src.
// EPB=16384 (74 blocks): per-(block,bucket) runs ~21 edges = 84 B >= one 64-B
// line -> pairs write traffic ~7 MB (was ~26 MB at EPB=2048: 410K sub-line
// runs), global bucket atomics 410K -> 58K.  [r11 lesson: write density]
// Blocks 0..31 also zero the pooled accumulator (consumed by k_gather2p).
__global__ void k_bscatter(const int* __restrict__ src, const int* __restrict__ dst,
                           int* __restrict__ bcnt, int* __restrict__ pairs,
                           float* __restrict__ pooled) {
    __shared__ int h[NB];
    if (blockIdx.x < (N_GRAPHS * HID_C) / 512)
        pooled[blockIdx.x * 512 + threadIdx.x] = 0.f;
    for (int i = threadIdx.x; i < NB; i += blockDim.x) h[i] = 0;
    __syncthreads();
    int e0 = blockIdx.x * EPB;
    int e1 = e0 + EPB; if (e1 > N_EDGES) e1 = N_EDGES;
    for (int e = e0 + threadIdx.x; e < e1; e += blockDim.x)
        atomicAdd(&h[dst[e] >> BSH], 1);
    __syncthreads();
    for (int i = threadIdx.x; i < NB; i += blockDim.x)
        if (h[i]) h[i] = (i << 11) + atomicAdd(&bcnt[i], h[i]);
    __syncthreads();
    for (int e = e0 + threadIdx.x; e < e1; e += blockDim.x) {
        int d = dst[e];
        int pos = atomicAdd(&h[d >> BSH], 1);
        pairs[pos] = ((d & (BNODES - 1)) << 17) | src[e];
    }
}

// ---- per-bucket counting sort -> CSR + rs/cnt/dinv, epilogue writes
// xs[node] = x[node] * dinv[node]  (fp32, rows padded to 8 floats).
// v2: bucket staged in LDS (pairs read ONCE), placement into LDS ssorted,
// csr written out dense+coalesced (was scattered global-latency chains).
__global__ void k_bsort_xs(const int* __restrict__ pairs, const int* __restrict__ bcnt,
                           const float* __restrict__ x,
                           int* __restrict__ csr, int* __restrict__ rs,
                           int* __restrict__ cnt, float* __restrict__ dinv,
                           float* __restrict__ xs) {
    __shared__ int spairs[CAPB];        // 8 KB
    __shared__ int ssorted[CAPB];       // 8 KB
    __shared__ int hist[BNODES];
    __shared__ int tmp[BNODES];
    __shared__ int cur[BNODES];
    __shared__ float sdv[BNODES];
    int b = blockIdx.x;
    int t = threadIdx.x;
    int base = b << BSH;
    if (t < BNODES) hist[t] = 0;
    __syncthreads();
    int s = b << 11;            // fixed bucket start
    int n = bcnt[b];
    if (n > CAPB) n = CAPB;     // safety clamp (13-sigma headroom)
    for (int i = t; i < n; i += 256) {
        int p = pairs[s + i];
        spairs[i] = p;
        atomicAdd(&hist[p >> 17], 1);
    }
    __syncthreads();
    int v = (t < BNODES) ? hist[t] : 0;
    if (t < BNODES) tmp[t] = v;
    __syncthreads();
    for (int off = 1; off < BNODES; off <<= 1) {
        int a = (t < BNODES && t >= off) ? tmp[t - off] : 0;
        __syncthreads();
        if (t < BNODES) tmp[t] += a;
        __syncthreads();
    }
    float dv_t = rsqrtf((float)v + 1.0f);
    if (t < BNODES) {
        cur[t] = tmp[t] - v;    // LOCAL exclusive offset
        sdv[t] = dv_t;
        if (base + t < N_NODES) {
            rs[base + t] = s + tmp[t] - v;
            cnt[base + t] = v;
            dinv[base + t] = dv_t;
        }
    }
    __syncthreads();
    for (int i = t; i < n; i += 256) {
        int p = spairs[i];
        int pos = atomicAdd(&cur[p >> 17], 1);
        ssorted[pos] = p & 0x1FFFF;
    }
    __syncthreads();
    for (int i = t; i < n; i += 256)
        csr[s + i] = ssorted[i];          // dense coalesced write-out
    // ---- xs epilogue: xs[node*8+k] = x[node*5+k] * dinv[node], k<5 ----
    for (int i = t; i < BNODES * 8; i += 256) {
        int nl = i >> 3, k = i & 7;
        int node = base + nl;
        if (node < N_NODES && k < IN_C)
            xs[(unsigned)node * 8 + k] = x[(unsigned)node * IN_C + k] * sdv[nl];
    }
}

// ---- fused layer-1: 5-dim gather (L2-resident xs table) + @W1 + relu + @W2,
// writes g2tab (bf16x2 packed). W1/W2 columns live in REGISTERS (each lane
// owns a fixed channel pair), h-row bounces through LDS as broadcast b128 reads.
__global__ void __launch_bounds__(256) k_l1(
        const float* __restrict__ xs, const int* __restrict__ csr,
        const int* __restrict__ rs, const int* __restrict__ cnt,
        const float* __restrict__ dinv, const float* __restrict__ b1,
        const float* __restrict__ W1, const float* __restrict__ W2,
        uint32* __restrict__ g2t) {
    __shared__ __align__(16) float sagg[4][L1NPW][8];   // 1 KB
    __shared__ __align__(16) float srow[4][2][HID_C];   // 2 KB
    int tid = threadIdx.x;
    int w = tid >> 6;
    int lane = tid & 63;
    int base = (blockIdx.x * 4 + w) * L1NPW;

    // ---- gather phase: 8 lanes per node, fp32 5-vec accumulate (pipelined) ----
    int g = lane >> 3, l = lane & 7;
    int v = base + g;
    float a0 = 0.f, a1 = 0.f, a2 = 0.f, a3 = 0.f, a4 = 0.f;
    if (v < N_NODES) {
        int k0 = rs[v];
        int n = cnt[v];
        if (l == 0) {           // self-loop contribution
            float4 p = *(const float4*)&xs[(unsigned)v * 8];
            a0 = p.x; a1 = p.y; a2 = p.z; a3 = p.w;
            a4 = xs[(unsigned)v * 8 + 4];
        }
        int i = l;
        int un = (i < n) ? csr[k0 + i] : -1;
        while (un >= 0) {
            int u = un;
            i += 8;
            un = (i < n) ? csr[k0 + i] : -1;   // next csr overlaps this xs gather
            float4 p = *(const float4*)&xs[(unsigned)u * 8];
            float p4 = xs[(unsigned)u * 8 + 4];
            a0 += p.x; a1 += p.y; a2 += p.z; a3 += p.w; a4 += p4;
        }
    }
#pragma unroll
    for (int off = 4; off; off >>= 1) {
        a0 += __shfl_xor(a0, off);
        a1 += __shfl_xor(a1, off);
        a2 += __shfl_xor(a2, off);
        a3 += __shfl_xor(a3, off);
        a4 += __shfl_xor(a4, off);
    }
    if (l == 0 && v < N_NODES) {
        *(float4*)&sagg[w][g][0] = make_float4(a0, a1, a2, a3);
        sagg[w][g][4] = a4;
    }

    // ---- weight columns -> registers (static indexing only) ----
    int half = lane >> 5, c2 = lane & 31;
    int kb = half << 5;
    float2 w1r[IN_C];
#pragma unroll
    for (int k = 0; k < IN_C; ++k)
        w1r[k] = *(const float2*)&W1[k * HID_C + 2 * c2];
    float2 w2r[32];
#pragma unroll
    for (int j = 0; j < 32; ++j)
        w2r[j] = *(const float2*)&W2[(kb + j) * HID_C + 2 * c2];
    float2 bias = *(const float2*)&b1[2 * c2];

    // ---- dense phase: h1 = relu(dinv*(agg@W1)+b1); g2 = bf16(dinv*(h1@W2)) ----
    for (int gg = 0; gg < L1NPW; ++gg) {
        int node = base + gg;                 // base wave-uniform -> uniform break
        if (node >= N_NODES) break;
        float dv = dinv[node];
        float4 qa = *(const float4*)&sagg[w][gg][0];
        float q4 = sagg[w][gg][4];
        float s0 = qa.x * w1r[0].x + qa.y * w1r[1].x + qa.z * w1r[2].x
                 + qa.w * w1r[3].x + q4 * w1r[4].x;
        float s1 = qa.x * w1r[0].y + qa.y * w1r[1].y + qa.z * w1r[2].y
                 + qa.w * w1r[3].y + q4 * w1r[4].y;
        float h0 = fmaxf(s0 * dv + bias.x, 0.f);
        float h1 = fmaxf(s1 * dv + bias.y, 0.f);
        int buf = gg & 1;
        if (half == 0) *(float2*)&srow[w][buf][2 * c2] = make_float2(h0, h1);
        float t0 = 0.f, t1 = 0.f;
#pragma unroll
        for (int jj = 0; jj < 8; ++jj) {
            float4 hv = *(const float4*)&srow[w][buf][kb + 4 * jj];  // broadcast
            t0 += hv.x * w2r[4 * jj + 0].x + hv.y * w2r[4 * jj + 1].x
                + hv.z * w2r[4 * jj + 2].x + hv.w * w2r[4 * jj + 3].x;
            t1 += hv.x * w2r[4 * jj + 0].y + hv.y * w2r[4 * jj + 1].y
                + hv.z * w2r[4 * jj + 2].y + hv.w * w2r[4 * jj + 3].y;
        }
        t0 += __shfl_xor(t0, 32);
        t1 += __shfl_xor(t1, 32);
        if (half == 0)
            g2t[(unsigned)node * 32 + c2] = (f2bf(t1 * dv) << 16) | f2bf(t0 * dv);
    }
}

// ---- gather layer 2 fused with relu + mean-pool accumulate (v5).
// Each lane owns TWO nodes (va = n0+sub, vb = n0+4+sub), fused body with
// 8+8 = 16 independent gathers in flight; uniform-wave shuffle-merged flush.
#define LDU2(d, u) uint2 d = *(const uint2*)&g[(unsigned)(u) * 32 + 2 * c4]
#define ACC4(s0, s1, s2, s3, r) { s0 += bflo(r.x); s1 += bfhi(r.x); \
                                  s2 += bflo(r.y); s3 += bfhi(r.y); }
__global__ void __launch_bounds__(256, 4) k_gather2p(
        const uint32* __restrict__ g, const int* __restrict__ csr,
        const int* __restrict__ rs, const int* __restrict__ cnt,
        const float* __restrict__ dinv, const float* __restrict__ b,
        const int* __restrict__ batch, float* __restrict__ pooled) {
    int wv = __builtin_amdgcn_readfirstlane(
        blockIdx.x * (blockDim.x >> 6) + (threadIdx.x >> 6));
    int n0 = wv * GNPW;
    if (n0 >= N_NODES) return;            // grid exact: 12500*8 == N_NODES
    int lane = threadIdx.x & 63;
    int sub = lane >> 4;                  // node slot (0..3)
    int c4 = lane & 15;                   // channel-quad index
    int va = n0 + sub, vb = n0 + 4 + sub;
    int ka = rs[va], na = cnt[va];
    int kb = rs[vb], nb = cnt[vb];
    float dva = dinv[va], dvb = dinv[vb];
    int ga = batch[va], gb = batch[vb];
    float4 bias = *(const float4*)&b[4 * c4];
    LDU2(rsa, va); LDU2(rsb, vb);         // self-loops
    float a0 = bflo(rsa.x), a1 = bfhi(rsa.x), a2 = bflo(rsa.y), a3 = bfhi(rsa.y);
    float y0 = bflo(rsb.x), y1 = bfhi(rsb.x), y2 = bflo(rsb.y), y3 = bfhi(rsb.y);
    int ia = 0, ib = 0;
    while (ia + 7 < na && ib + 7 < nb) {
        int u0 = csr[ka+ia+0], u1 = csr[ka+ia+1], u2 = csr[ka+ia+2], u3 = csr[ka+ia+3];
        int u4 = csr[ka+ia+4], u5 = csr[ka+ia+5], u6 = csr[ka+ia+6], u7 = csr[ka+ia+7];
        int w0 = csr[kb+ib+0], w1 = csr[kb+ib+1], w2 = csr[kb+ib+2], w3 = csr[kb+ib+3];
        int w4 = csr[kb+ib+4], w5 = csr[kb+ib+5], w6 = csr[kb+ib+6], w7 = csr[kb+ib+7];
        LDU2(p0, u0); LDU2(p1, u1); LDU2(p2, u2); LDU2(p3, u3);
        LDU2(p4, u4); LDU2(p5, u5); LDU2(p6, u6); LDU2(p7, u7);
        LDU2(q0, w0); LDU2(q1, w1); LDU2(q2, w2); LDU2(q3, w3);
        LDU2(q4, w4); LDU2(q5, w5); LDU2(q6, w6); LDU2(q7, w7);
        ACC4(a0, a1, a2, a3, p0); ACC4(a0, a1, a2, a3, p1);
        ACC4(a0, a1, a2, a3, p2); ACC4(a0, a1, a2, a3, p3);
        ACC4(a0, a1, a2, a3, p4); ACC4(a0, a1, a2, a3, p5);
        ACC4(a0, a1, a2, a3, p6); ACC4(a0, a1, a2, a3, p7);
        ACC4(y0, y1, y2, y3, q0); ACC4(y0, y1, y2, y3, q1);
        ACC4(y0, y1, y2, y3, q2); ACC4(y0, y1, y2, y3, q3);
        ACC4(y0, y1, y2, y3, q4); ACC4(y0, y1, y2, y3, q5);
        ACC4(y0, y1, y2, y3, q6); ACC4(y0, y1, y2, y3, q7);
        ia += 8; ib += 8;
    }
    while (ia + 7 < na) {
        int u0 = csr[ka+ia+0], u1 = csr[ka+ia+1], u2 = csr[ka+ia+2], u3 = csr[ka+ia+3];
        int u4 = csr[ka+ia+4], u5 = csr[ka+ia+5], u6 = csr[ka+ia+6], u7 = csr[ka+ia+7];
        LDU2(p0, u0); LDU2(p1, u1); LDU2(p2, u2); LDU2(p3, u3);
        LDU2(p4, u4); LDU2(p5, u5); LDU2(p6, u6); LDU2(p7, u7);
        ACC4(a0, a1, a2, a3, p0); ACC4(a0, a1, a2, a3, p1);
        ACC4(a0, a1, a2, a3, p2); ACC4(a0, a1, a2, a3, p3);
        ACC4(a0, a1, a2, a3, p4); ACC4(a0, a1, a2, a3, p5);
        ACC4(a0, a1, a2, a3, p6); ACC4(a0, a1, a2, a3, p7);
        ia += 8;
    }
    while (ib + 7 < nb) {
        int w0 = csr[kb+ib+0], w1 = csr[kb+ib+1], w2 = csr[kb+ib+2], w3 = csr[kb+ib+3];
        int w4 = csr[kb+ib+4], w5 = csr[kb+ib+5], w6 = csr[kb+ib+6], w7 = csr[kb+ib+7];
        LDU2(q0, w0); LDU2(q1, w1); LDU2(q2, w2); LDU2(q3, w3);
        LDU2(q4, w4); LDU2(q5, w5); LDU2(q6, w6); LDU2(q7, w7);
        ACC4(y0, y1, y2, y3, q0); ACC4(y0, y1, y2, y3, q1);
        ACC4(y0, y1, y2, y3, q2); ACC4(y0, y1, y2, y3, q3);
        ACC4(y0, y1, y2, y3, q4); ACC4(y0, y1, y2, y3, q5);
        ACC4(y0, y1, y2, y3, q6); ACC4(y0, y1, y2, y3, q7);
        ib += 8;
    }
    while (ia + 3 < na && ib + 3 < nb) {
        int u0 = csr[ka+ia+0], u1 = csr[ka+ia+1], u2 = csr[ka+ia+2], u3 = csr[ka+ia+3];
        int w0 = csr[kb+ib+0], w1 = csr[kb+ib+1], w2 = csr[kb+ib+2], w3 = csr[kb+ib+3];
        LDU2(p0, u0); LDU2(p1, u1); LDU2(p2, u2); LDU2(p3, u3);
        LDU2(q0, w0); LDU2(q1, w1); LDU2(q2, w2); LDU2(q3, w3);
        ACC4(a0, a1, a2, a3, p0); ACC4(a0, a1, a2, a3, p1);
        ACC4(a0, a1, a2, a3, p2); ACC4(a0, a1, a2, a3, p3);
        ACC4(y0, y1, y2, y3, q0); ACC4(y0, y1, y2, y3, q1);
        ACC4(y0, y1, y2, y3, q2); ACC4(y0, y1, y2, y3, q3);
        ia += 4; ib += 4;
    }
    while (ia + 3 < na) {
        int u0 = csr[ka+ia+0], u1 = csr[ka+ia+1], u2 = csr[ka+ia+2], u3 = csr[ka+ia+3];
        LDU2(p0, u0); LDU2(p1, u1); LDU2(p2, u2); LDU2(p3, u3);
        ACC4(a0, a1, a2, a3, p0); ACC4(a0, a1, a2, a3, p1);
        ACC4(a0, a1, a2, a3, p2); ACC4(a0, a1, a2, a3, p3);
        ia += 4;
    }
    while (ib + 3 < nb) {
        int w0 = csr[kb+ib+0], w1 = csr[kb+ib+1], w2 = csr[kb+ib+2], w3 = csr[kb+ib+3];
        LDU2(q0, w0); LDU2(q1, w1); LDU2(q2, w2); LDU2(q3, w3);
        ACC4(y0, y1, y2, y3, q0); ACC4(y0, y1, y2, y3, q1);
        ACC4(y0, y1, y2, y3, q2); ACC4(y0, y1, y2, y3, q3);
        ib += 4;
    }
    while (ia < na && ib < nb) {
        int u0 = csr[ka + ia], w0 = csr[kb + ib];
        LDU2(p0, u0); LDU2(q0, w0);
        ACC4(a0, a1, a2, a3, p0); ACC4(y0, y1, y2, y3, q0);
        ++ia; ++ib;
    }
    while (ia < na) {
        LDU2(p0, csr[ka + ia]);
        ACC4(a0, a1, a2, a3, p0);
        ++ia;
    }
    while (ib < nb) {
        LDU2(q0, csr[kb + ib]);
        ACC4(y0, y1, y2, y3, q0);
        ++ib;
    }
    float oa0 = fmaxf(a0 * dva + bias.x, 0.f);
    float oa1 = fmaxf(a1 * dva + bias.y, 0.f);
    float oa2 = fmaxf(a2 * dva + bias.z, 0.f);
    float oa3 = fmaxf(a3 * dva + bias.w, 0.f);
    float ob0 = fmaxf(y0 * dvb + bias.x, 0.f);
    float ob1 = fmaxf(y1 * dvb + bias.y, 0.f);
    float ob2 = fmaxf(y2 * dvb + bias.z, 0.f);
    float ob3 = fmaxf(y3 * dvb + bias.w, 0.f);
    int g0 = __builtin_amdgcn_readfirstlane(ga);
    if (__all(ga == g0) && __all(gb == g0)) {      // ~98% of waves
        float f0 = oa0 + ob0, f1 = oa1 + ob1, f2 = oa2 + ob2, f3 = oa3 + ob3;
        f0 += __shfl_xor(f0, 16); f0 += __shfl_xor(f0, 32);
        f1 += __shfl_xor(f1, 16); f1 += __shfl_xor(f1, 32);
        f2 += __shfl_xor(f2, 16); f2 += __shfl_xor(f2, 32);
        f3 += __shfl_xor(f3, 16); f3 += __shfl_xor(f3, 32);
        if (sub == 0) {
            atomicAdd(&pooled[g0 * HID_C + 4 * c4 + 0], f0);
            atomicAdd(&pooled[g0 * HID_C + 4 * c4 + 1], f1);
            atomicAdd(&pooled[g0 * HID_C + 4 * c4 + 2], f2);
            atomicAdd(&pooled[g0 * HID_C + 4 * c4 + 3], f3);
        }
    } else {                                       // boundary wave: per-lane
        atomicAdd(&pooled[ga * HID_C + 4 * c4 + 0], oa0);
        atomicAdd(&pooled[ga * HID_C + 4 * c4 + 1], oa1);
        atomicAdd(&pooled[ga * HID_C + 4 * c4 + 2], oa2);
        atomicAdd(&pooled[ga * HID_C + 4 * c4 + 3], oa3);
        atomicAdd(&pooled[gb * HID_C + 4 * c4 + 0], ob0);
        atomicAdd(&pooled[gb * HID_C + 4 * c4 + 1], ob1);
        atomicAdd(&pooled[gb * HID_C + 4 * c4 + 2], ob2);
        atomicAdd(&pooled[gb * HID_C + 4 * c4 + 3], ob3);
    }
}

// ---- mean + FC; one block (64 thr) per graph (unchanged)
__global__ void k_fc(const float* __restrict__ pooled, const int* __restrict__ batch,
                     const float* __restrict__ Wfc, const float* __restrict__ bfc,
                     float* __restrict__ out) {
    int g = blockIdx.x;
    int c = threadIdx.x;
    int lo = 0, hi = N_NODES;
    while (lo < hi) { int mid = (lo + hi) >> 1; if (batch[mid] < g) lo = mid + 1; else hi = mid; }
    int start = lo;
    hi = N_NODES;
    while (lo < hi) { int mid = (lo + hi) >> 1; if (batch[mid] < g + 1) lo = mid + 1; else hi = mid; }
    int n = lo - start;
    float pv = pooled[g * HID_C + c] / (float)(n > 0 ? n : 1);
    float o0 = pv * Wfc[c * OUT_C + 0];
    float o1 = pv * Wfc[c * OUT_C + 1];
#pragma unroll
    for (int off = 32; off > 0; off >>= 1) {
        o0 += __shfl_down(o0, off);
        o1 += __shfl_down(o1, off);
    }
    if (c == 0) {
        out[g * OUT_C + 0] = o0 + bfc[0];
        out[g * OUT_C + 1] = o1 + bfc[1];
    }
}

extern "C" void kernel_launch(void* const* d_in, const int* in_sizes, int n_in,
                              void* d_out, int out_size, void* d_ws, size_t ws_size,
                              hipStream_t stream) {
    const float* x    = (const float*)d_in[0];
    const int*   ei   = (const int*)d_in[1];
    const int*   src  = ei;
    const int*   dst  = ei + N_EDGES;
    const int*   batch= (const int*)d_in[2];
    const float* W1   = (const float*)d_in[3];
    const float* b1   = (const float*)d_in[4];
    const float* W2   = (const float*)d_in[5];
    const float* b2   = (const float*)d_in[6];
    const float* Wfc  = (const float*)d_in[7];
    const float* bfc  = (const float*)d_in[8];
    float* out = (float*)d_out;

    // workspace layout (4B elems)
    float*  ws     = (float*)d_ws;
    int*    bcnt   = (int*)ws;                    // 1024
    float*  pooled = ws + 1024;                   // 16384 (zeroed by k_bscatter)
    float*  dinv   = pooled + 16384;              // 100352
    int*    cnt    = (int*)(dinv + 100352);       // 100352
    int*    rs     = cnt + 100352;                // 100352
    int*    pairs  = rs + 100352;                 // NB*CAPB = 1601536
    int*    csr    = pairs + (NB * CAPB);         // 1601536
    float*  xs     = (float*)(csr + (NB * CAPB)); // N*8 fp32 = 3.2 MB (16B-aligned)
    uint32* g2tab  = (uint32*)(xs + N_NODES * 8); // N*32 uint32 = 12.8 MB

    hipMemsetAsync(bcnt, 0, 1024 * sizeof(int), stream);

    // ---- CSR build + xs = x*dinv (fused; bucket-local sort keeps writes dense) ----
    k_bscatter<<<NBLK_E, 512, 0, stream>>>(src, dst, bcnt, pairs, pooled);
    k_bsort_xs<<<NB, 256, 0, stream>>>(pairs, bcnt, x, csr, rs, cnt, dinv, xs);

    // ---- layer-1: 5-dim gather + @W1 + relu + @W2 (fused; weights in regs) ----
    {
        int blocks = (N_NODES + 4 * L1NPW - 1) / (4 * L1NPW);   // 3125
        k_l1<<<blocks, 256, 0, stream>>>(xs, csr, rs, cnt, dinv, b1, W1, W2, g2tab);
    }

    // ---- layer-2 gather + relu + mean-pool (v5: 2 nodes/lane, 16 in flight) ----
    {
        int waves = (N_NODES + GNPW - 1) / GNPW;     // 12500
        int blocks = (waves + 3) / 4;                // 3125
        k_gather2p<<<blocks, 256, 0, stream>>>(g2tab, csr, rs, cnt, dinv, b2, batch, pooled);
    }

    // ---- FC ----
    k_fc<<<N_GRAPHS, 64, 0, stream>>>(pooled, batch, Wfc, bfc, out);
}

// Round 14
// 190.821 us; speedup vs baseline: 1.0869x; 1.0869x over previous
//
#include <hip/hip_runtime.h>

#define N_NODES 100000
#define N_EDGES 1200000
#define N_GRAPHS 256
#define IN_C 5
#define HID_C 64
#define OUT_C 2

#define BSH 7
#define BNODES 128
#define NB ((N_NODES + BNODES - 1) / BNODES)        // 782
#define CAPB 2048                                   // fixed bucket capacity (E=1534, sigma=39)
#define EPB 2048                                    // edges per chunk
#define NCHUNK ((N_EDGES + EPB - 1) / EPB)          // 586
#define SEGS 784                                    // seg row stride (782 buckets + total + pad)
#define GNPW 8                                      // nodes per wave in fused gather2+pool
#define L1NPW 8                                     // nodes per wave in k_l1

typedef unsigned int uint32;

// fp32 -> bf16 round-to-nearest-even (returns 16-bit pattern)
__device__ __forceinline__ uint32 f2bf(float f) {
    uint32 x = __float_as_uint(f);
    return (x + 0x7FFFu + ((x >> 16) & 1u)) >> 16;
}
__device__ __forceinline__ float bflo(uint32 r) { return __uint_as_float(r << 16); }
__device__ __forceinline__ float bfhi(uint32 r) { return __uint_as_float(r & 0xFFFF0000u); }

// ---- chunk counting-sort: sort each 2048-edge chunk by bucket IN LDS, write
// sorted chunk DENSE (chunk-major pairs) + per-chunk segment offsets (seg).
// No global atomics, no scattered global writes (r11/r13 lessons: scattered
// sub-line WRITES ping-pong L2 lines across XCDs; scattered READS are cheap
// -> moved to k_bsort's gather side). Blocks 0..63 also zero pooled.
__global__ void k_csort(const int* __restrict__ src, const int* __restrict__ dst,
                        int* __restrict__ pairs, int* __restrict__ seg,
                        float* __restrict__ pooled) {
    __shared__ int sp[EPB];          // 8 KB sorted payloads
    __shared__ int hist[782];
    __shared__ int st[256];
    int c = blockIdx.x, t = threadIdx.x;
    if (c < (N_GRAPHS * HID_C) / 256)
        pooled[c * 256 + t] = 0.f;
    for (int i = t; i < 782; i += 256) hist[i] = 0;
    __syncthreads();
    int e0 = c * EPB;
    int n = N_EDGES - e0; if (n > EPB) n = EPB;
    int pk[8], bk[8];
#pragma unroll
    for (int i = 0; i < 8; ++i) {
        int idx = t + i * 256;
        if (idx < n) {
            int d = dst[e0 + idx];
            bk[i] = d >> BSH;
            pk[i] = ((d & (BNODES - 1)) << 17) | src[e0 + idx];
            atomicAdd(&hist[bk[i]], 1);
        } else bk[i] = -1;
    }
    __syncthreads();
    // exclusive block-scan of hist[0..782), 4 elems/thread
    int i0 = t * 4;
    int v0 = (i0 + 0 < 782) ? hist[i0 + 0] : 0;
    int v1 = (i0 + 1 < 782) ? hist[i0 + 1] : 0;
    int v2 = (i0 + 2 < 782) ? hist[i0 + 2] : 0;
    int v3 = (i0 + 3 < 782) ? hist[i0 + 3] : 0;
    st[t] = v0 + v1 + v2 + v3;
    __syncthreads();
    for (int off = 1; off < 256; off <<= 1) {
        int a = (t >= off) ? st[t - off] : 0;
        __syncthreads();
        st[t] += a;
        __syncthreads();
    }
    int run = (t > 0) ? st[t - 1] : 0;
    if (i0 + 0 < 782) { hist[i0 + 0] = run; seg[c * SEGS + i0 + 0] = run; run += v0; }
    if (i0 + 1 < 782) { hist[i0 + 1] = run; seg[c * SEGS + i0 + 1] = run; run += v1; }
    if (i0 + 2 < 782) { hist[i0 + 2] = run; seg[c * SEGS + i0 + 2] = run; run += v2; }
    if (i0 + 3 < 782) { hist[i0 + 3] = run; seg[c * SEGS + i0 + 3] = run; run += v3; }
    if (t == 0) seg[c * SEGS + 782] = n;
    __syncthreads();
    // placement into LDS (hist doubles as cursor)
#pragma unroll
    for (int i = 0; i < 8; ++i)
        if (bk[i] >= 0) {
            int pos = atomicAdd(&hist[bk[i]], 1);
            sp[pos] = pk[i];
        }
    __syncthreads();
    for (int i = t; i < n; i += 256)
        pairs[c * EPB + i] = sp[i];      // dense coalesced write-out
}

// ---- per-bucket counting sort -> CSR + rs/cnt/dinv + xs epilogue.
// v3: gathers the bucket's 586 chunk-segments (scattered ~10 B READS) into
// LDS, then the proven v2 LDS counting sort + dense csr write-out.
__global__ void k_bsort_xs(const int* __restrict__ pairs, const int* __restrict__ seg,
                           const float* __restrict__ x,
                           int* __restrict__ csr, int* __restrict__ rs,
                           int* __restrict__ cnt, float* __restrict__ dinv,
                           float* __restrict__ xs) {
    __shared__ int spairs[CAPB];        // 8 KB
    __shared__ int ssorted[CAPB];       // 8 KB
    __shared__ int slen[NCHUNK];        // 2.3 KB
    __shared__ int ssrc[NCHUNK];        // 2.3 KB (global src offset within chunk)
    __shared__ int sdst[NCHUNK];        // 2.3 KB (dst offset in spairs)
    __shared__ int st[256];
    __shared__ int hist[BNODES];
    __shared__ int tmp[BNODES];
    __shared__ int cur[BNODES];
    __shared__ float sdv[BNODES];
    int b = blockIdx.x;
    int t = threadIdx.x;
    int base = b << BSH;
    // A: read per-chunk segment bounds for this bucket
    for (int c = t; c < NCHUNK; c += 256) {
        int s0 = seg[c * SEGS + b];
        int s1 = seg[c * SEGS + b + 1];
        slen[c] = s1 - s0;
        ssrc[c] = c * EPB + s0;
    }
    if (t < BNODES) hist[t] = 0;
    __syncthreads();
    // B: exclusive scan of slen[0..586), 4 elems/thread
    int i0 = t * 4;
    int v0 = (i0 + 0 < NCHUNK) ? slen[i0 + 0] : 0;
    int v1 = (i0 + 1 < NCHUNK) ? slen[i0 + 1] : 0;
    int v2 = (i0 + 2 < NCHUNK) ? slen[i0 + 2] : 0;
    int v3 = (i0 + 3 < NCHUNK) ? slen[i0 + 3] : 0;
    st[t] = v0 + v1 + v2 + v3;
    __syncthreads();
    for (int off = 1; off < 256; off <<= 1) {
        int a = (t >= off) ? st[t - off] : 0;
        __syncthreads();
        st[t] += a;
        __syncthreads();
    }
    int run = (t > 0) ? st[t - 1] : 0;
    if (i0 + 0 < NCHUNK) { sdst[i0 + 0] = run; run += v0; }
    if (i0 + 1 < NCHUNK) { sdst[i0 + 1] = run; run += v1; }
    if (i0 + 2 < NCHUNK) { sdst[i0 + 2] = run; run += v2; }
    if (i0 + 3 < NCHUNK) { sdst[i0 + 3] = run; run += v3; }
    __syncthreads();
    int n = st[255];                    // bucket total
    if (n > CAPB) n = CAPB;             // safety clamp (13-sigma headroom)
    // C: gather segments into spairs + histogram
    for (int c = t; c < NCHUNK; c += 256) {
        int L = slen[c], gs = ssrc[c], d0 = sdst[c];
        for (int j = 0; j < L; ++j) {
            int p = pairs[gs + j];
            if (d0 + j < CAPB) {
                spairs[d0 + j] = p;
                atomicAdd(&hist[p >> 17], 1);
            }
        }
    }
    __syncthreads();
    // D: per-node counting sort (proven v2 path)
    int v = (t < BNODES) ? hist[t] : 0;
    if (t < BNODES) tmp[t] = v;
    __syncthreads();
    for (int off = 1; off < BNODES; off <<= 1) {
        int a = (t < BNODES && t >= off) ? tmp[t - off] : 0;
        __syncthreads();
        if (t < BNODES) tmp[t] += a;
        __syncthreads();
    }
    float dv_t = rsqrtf((float)v + 1.0f);
    int s = b << 11;                    // fixed bucket start in csr
    if (t < BNODES) {
        cur[t] = tmp[t] - v;
        sdv[t] = dv_t;
        if (base + t < N_NODES) {
            rs[base + t] = s + tmp[t] - v;
            cnt[base + t] = v;
            dinv[base + t] = dv_t;
        }
    }
    __syncthreads();
    for (int i = t; i < n; i += 256) {
        int p = spairs[i];
        int pos = atomicAdd(&cur[p >> 17], 1);
        ssorted[pos] = p & 0x1FFFF;
    }
    __syncthreads();
    for (int i = t; i < n; i += 256)
        csr[s + i] = ssorted[i];        // dense coalesced write-out
    // ---- xs epilogue: xs[node*8+k] = x[node*5+k] * dinv[node], k<5 ----
    for (int i = t; i < BNODES * 8; i += 256) {
        int nl = i >> 3, k = i & 7;
        int node = base + nl;
        if (node < N_NODES && k < IN_C)
            xs[(unsigned)node * 8 + k] = x[(unsigned)node * IN_C + k] * sdv[nl];
    }
}

// ---- fused layer-1: 5-dim gather (L2-resident xs table) + @W1 + relu + @W2,
// writes g2tab (bf16x2 packed). W1/W2 columns live in REGISTERS (each lane
// owns a fixed channel pair), h-row bounces through LDS as broadcast b128 reads.
__global__ void __launch_bounds__(256) k_l1(
        const float* __restrict__ xs, const int* __restrict__ csr,
        const int* __restrict__ rs, const int* __restrict__ cnt,
        const float* __restrict__ dinv, const float* __restrict__ b1,
        const float* __restrict__ W1, const float* __restrict__ W2,
        uint32* __restrict__ g2t) {
    __shared__ __align__(16) float sagg[4][L1NPW][8];   // 1 KB
    __shared__ __align__(16) float srow[4][2][HID_C];   // 2 KB
    int tid = threadIdx.x;
    int w = tid >> 6;
    int lane = tid & 63;
    int base = (blockIdx.x * 4 + w) * L1NPW;

    // ---- gather phase: 8 lanes per node, fp32 5-vec accumulate (pipelined) ----
    int g = lane >> 3, l = lane & 7;
    int v = base + g;
    float a0 = 0.f, a1 = 0.f, a2 = 0.f, a3 = 0.f, a4 = 0.f;
    if (v < N_NODES) {
        int k0 = rs[v];
        int n = cnt[v];
        if (l == 0) {           // self-loop contribution
            float4 p = *(const float4*)&xs[(unsigned)v * 8];
            a0 = p.x; a1 = p.y; a2 = p.z; a3 = p.w;
            a4 = xs[(unsigned)v * 8 + 4];
        }
        int i = l;
        int un = (i < n) ? csr[k0 + i] : -1;
        while (un >= 0) {
            int u = un;
            i += 8;
            un = (i < n) ? csr[k0 + i] : -1;   // next csr overlaps this xs gather
            float4 p = *(const float4*)&xs[(unsigned)u * 8];
            float p4 = xs[(unsigned)u * 8 + 4];
            a0 += p.x; a1 += p.y; a2 += p.z; a3 += p.w; a4 += p4;
        }
    }
#pragma unroll
    for (int off = 4; off; off >>= 1) {
        a0 += __shfl_xor(a0, off);
        a1 += __shfl_xor(a1, off);
        a2 += __shfl_xor(a2, off);
        a3 += __shfl_xor(a3, off);
        a4 += __shfl_xor(a4, off);
    }
    if (l == 0 && v < N_NODES) {
        *(float4*)&sagg[w][g][0] = make_float4(a0, a1, a2, a3);
        sagg[w][g][4] = a4;
    }

    // ---- weight columns -> registers (static indexing only) ----
    int half = lane >> 5, c2 = lane & 31;
    int kb = half << 5;
    float2 w1r[IN_C];
#pragma unroll
    for (int k = 0; k < IN_C; ++k)
        w1r[k] = *(const float2*)&W1[k * HID_C + 2 * c2];
    float2 w2r[32];
#pragma unroll
    for (int j = 0; j < 32; ++j)
        w2r[j] = *(const float2*)&W2[(kb + j) * HID_C + 2 * c2];
    float2 bias = *(const float2*)&b1[2 * c2];

    // ---- dense phase: h1 = relu(dinv*(agg@W1)+b1); g2 = bf16(dinv*(h1@W2)) ----
    for (int gg = 0; gg < L1NPW; ++gg) {
        int node = base + gg;                 // base wave-uniform -> uniform break
        if (node >= N_NODES) break;
        float dv = dinv[node];
        float4 qa = *(const float4*)&sagg[w][gg][0];
        float q4 = sagg[w][gg][4];
        float s0 = qa.x * w1r[0].x + qa.y * w1r[1].x + qa.z * w1r[2].x
                 + qa.w * w1r[3].x + q4 * w1r[4].x;
        float s1 = qa.x * w1r[0].y + qa.y * w1r[1].y + qa.z * w1r[2].y
                 + qa.w * w1r[3].y + q4 * w1r[4].y;
        float h0 = fmaxf(s0 * dv + bias.x, 0.f);
        float h1 = fmaxf(s1 * dv + bias.y, 0.f);
        int buf = gg & 1;
        if (half == 0) *(float2*)&srow[w][buf][2 * c2] = make_float2(h0, h1);
        float t0 = 0.f, t1 = 0.f;
#pragma unroll
        for (int jj = 0; jj < 8; ++jj) {
            float4 hv = *(const float4*)&srow[w][buf][kb + 4 * jj];  // broadcast
            t0 += hv.x * w2r[4 * jj + 0].x + hv.y * w2r[4 * jj + 1].x
                + hv.z * w2r[4 * jj + 2].x + hv.w * w2r[4 * jj + 3].x;
            t1 += hv.x * w2r[4 * jj + 0].y + hv.y * w2r[4 * jj + 1].y
                + hv.z * w2r[4 * jj + 2].y + hv.w * w2r[4 * jj + 3].y;
        }
        t0 += __shfl_xor(t0, 32);
        t1 += __shfl_xor(t1, 32);
        if (half == 0)
            g2t[(unsigned)node * 32 + c2] = (f2bf(t1 * dv) << 16) | f2bf(t0 * dv);
    }
}

// ---- gather layer 2 fused with relu + mean-pool accumulate (v5).
// Each lane owns TWO nodes (va = n0+sub, vb = n0+4+sub), fused body with
// 8+8 = 16 independent gathers in flight; uniform-wave shuffle-merged flush.
#define LDU2(d, u) uint2 d = *(const uint2*)&g[(unsigned)(u) * 32 + 2 * c4]
#define ACC4(s0, s1, s2, s3, r) { s0 += bflo(r.x); s1 += bfhi(r.x); \
                                  s2 += bflo(r.y); s3 += bfhi(r.y); }
__global__ void __launch_bounds__(256, 4) k_gather2p(
        const uint32* __restrict__ g, const int* __restrict__ csr,
        const int* __restrict__ rs, const int* __restrict__ cnt,
        const float* __restrict__ dinv, const float* __restrict__ b,
        const int* __restrict__ batch, float* __restrict__ pooled) {
    int wv = __builtin_amdgcn_readfirstlane(
        blockIdx.x * (blockDim.x >> 6) + (threadIdx.x >> 6));
    int n0 = wv * GNPW;
    if (n0 >= N_NODES) return;            // grid exact: 12500*8 == N_NODES
    int lane = threadIdx.x & 63;
    int sub = lane >> 4;                  // node slot (0..3)
    int c4 = lane & 15;                   // channel-quad index
    int va = n0 + sub, vb = n0 + 4 + sub;
    int ka = rs[va], na = cnt[va];
    int kb = rs[vb], nb = cnt[vb];
    float dva = dinv[va], dvb = dinv[vb];
    int ga = batch[va], gb = batch[vb];
    float4 bias = *(const float4*)&b[4 * c4];
    LDU2(rsa, va); LDU2(rsb, vb);         // self-loops
    float a0 = bflo(rsa.x), a1 = bfhi(rsa.x), a2 = bflo(rsa.y), a3 = bfhi(rsa.y);
    float y0 = bflo(rsb.x), y1 = bfhi(rsb.x), y2 = bflo(rsb.y), y3 = bfhi(rsb.y);
    int ia = 0, ib = 0;
    while (ia + 7 < na && ib + 7 < nb) {
        int u0 = csr[ka+ia+0], u1 = csr[ka+ia+1], u2 = csr[ka+ia+2], u3 = csr[ka+ia+3];
        int u4 = csr[ka+ia+4], u5 = csr[ka+ia+5], u6 = csr[ka+ia+6], u7 = csr[ka+ia+7];
        int w0 = csr[kb+ib+0], w1 = csr[kb+ib+1], w2 = csr[kb+ib+2], w3 = csr[kb+ib+3];
        int w4 = csr[kb+ib+4], w5 = csr[kb+ib+5], w6 = csr[kb+ib+6], w7 = csr[kb+ib+7];
        LDU2(p0, u0); LDU2(p1, u1); LDU2(p2, u2); LDU2(p3, u3);
        LDU2(p4, u4); LDU2(p5, u5); LDU2(p6, u6); LDU2(p7, u7);
        LDU2(q0, w0); LDU2(q1, w1); LDU2(q2, w2); LDU2(q3, w3);
        LDU2(q4, w4); LDU2(q5, w5); LDU2(q6, w6); LDU2(q7, w7);
        ACC4(a0, a1, a2, a3, p0); ACC4(a0, a1, a2, a3, p1);
        ACC4(a0, a1, a2, a3, p2); ACC4(a0, a1, a2, a3, p3);
        ACC4(a0, a1, a2, a3, p4); ACC4(a0, a1, a2, a3, p5);
        ACC4(a0, a1, a2, a3, p6); ACC4(a0, a1, a2, a3, p7);
        ACC4(y0, y1, y2, y3, q0); ACC4(y0, y1, y2, y3, q1);
        ACC4(y0, y1, y2, y3, q2); ACC4(y0, y1, y2, y3, q3);
        ACC4(y0, y1, y2, y3, q4); ACC4(y0, y1, y2, y3, q5);
        ACC4(y0, y1, y2, y3, q6); ACC4(y0, y1, y2, y3, q7);
        ia += 8; ib += 8;
    }
    while (ia + 7 < na) {
        int u0 = csr[ka+ia+0], u1 = csr[ka+ia+1], u2 = csr[ka+ia+2], u3 = csr[ka+ia+3];
        int u4 = csr[ka+ia+4], u5 = csr[ka+ia+5], u6 = csr[ka+ia+6], u7 = csr[ka+ia+7];
        LDU2(p0, u0); LDU2(p1, u1); LDU2(p2, u2); LDU2(p3, u3);
        LDU2(p4, u4); LDU2(p5, u5); LDU2(p6, u6); LDU2(p7, u7);
        ACC4(a0, a1, a2, a3, p0); ACC4(a0, a1, a2, a3, p1);
        ACC4(a0, a1, a2, a3, p2); ACC4(a0, a1, a2, a3, p3);
        ACC4(a0, a1, a2, a3, p4); ACC4(a0, a1, a2, a3, p5);
        ACC4(a0, a1, a2, a3, p6); ACC4(a0, a1, a2, a3, p7);
        ia += 8;
    }
    while (ib + 7 < nb) {
        int w0 = csr[kb+ib+0], w1 = csr[kb+ib+1], w2 = csr[kb+ib+2], w3 = csr[kb+ib+3];
        int w4 = csr[kb+ib+4], w5 = csr[kb+ib+5], w6 = csr[kb+ib+6], w7 = csr[kb+ib+7];
        LDU2(q0, w0); LDU2(q1, w1); LDU2(q2, w2); LDU2(q3, w3);
        LDU2(q4, w4); LDU2(q5, w5); LDU2(q6, w6); LDU2(q7, w7);
        ACC4(y0, y1, y2, y3, q0); ACC4(y0, y1, y2, y3, q1);
        ACC4(y0, y1, y2, y3, q2); ACC4(y0, y1, y2, y3, q3);
        ACC4(y0, y1, y2, y3, q4); ACC4(y0, y1, y2, y3, q5);
        ACC4(y0, y1, y2, y3, q6); ACC4(y0, y1, y2, y3, q7);
        ib += 8;
    }
    while (ia + 3 < na && ib + 3 < nb) {
        int u0 = csr[ka+ia+0], u1 = csr[ka+ia+1], u2 = csr[ka+ia+2], u3 = csr[ka+ia+3];
        int w0 = csr[kb+ib+0], w1 = csr[kb+ib+1], w2 = csr[kb+ib+2], w3 = csr[kb+ib+3];
        LDU2(p0, u0); LDU2(p1, u1); LDU2(p2, u2); LDU2(p3, u3);
        LDU2(q0, w0); LDU2(q1, w1); LDU2(q2, w2); LDU2(q3, w3);
        ACC4(a0, a1, a2, a3, p0); ACC4(a0, a1, a2, a3, p1);
        ACC4(a0, a1, a2, a3, p2); ACC4(a0, a1, a2, a3, p3);
        ACC4(y0, y1, y2, y3, q0); ACC4(y0, y1, y2, y3, q1);
        ACC4(y0, y1, y2, y3, q2); ACC4(y0, y1, y2, y3, q3);
        ia += 4; ib += 4;
    }
    while (ia + 3 < na) {
        int u0 = csr[ka+ia+0], u1 = csr[ka+ia+1], u2 = csr[ka+ia+2], u3 = csr[ka+ia+3];
        LDU2(p0, u0); LDU2(p1, u1); LDU2(p2, u2); LDU2(p3, u3);
        ACC4(a0, a1, a2, a3, p0); ACC4(a0, a1, a2, a3, p1);
        ACC4(a0, a1, a2, a3, p2); ACC4(a0, a1, a2, a3, p3);
        ia += 4;
    }
    while (ib + 3 < nb) {
        int w0 = csr[kb+ib+0], w1 = csr[kb+ib+1], w2 = csr[kb+ib+2], w3 = csr[kb+ib+3];
        LDU2(q0, w0); LDU2(q1, w1); LDU2(q2, w2); LDU2(q3, w3);
        ACC4(y0, y1, y2, y3, q0); ACC4(y0, y1, y2, y3, q1);
        ACC4(y0, y1, y2, y3, q2); ACC4(y0, y1, y2, y3, q3);
        ib += 4;
    }
    while (ia < na && ib < nb) {
        int u0 = csr[ka + ia], w0 = csr[kb + ib];
        LDU2(p0, u0); LDU2(q0, w0);
        ACC4(a0, a1, a2, a3, p0); ACC4(y0, y1, y2, y3, q0);
        ++ia; ++ib;
    }
    while (ia < na) {
        LDU2(p0, csr[ka + ia]);
        ACC4(a0, a1, a2, a3, p0);
        ++ia;
    }
    while (ib < nb) {
        LDU2(q0, csr[kb + ib]);
        ACC4(y0, y1, y2, y3, q0);
        ++ib;
    }
    float oa0 = fmaxf(a0 * dva + bias.x, 0.f);
    float oa1 = fmaxf(a1 * dva + bias.y, 0.f);
    float oa2 = fmaxf(a2 * dva + bias.z, 0.f);
    float oa3 = fmaxf(a3 * dva + bias.w, 0.f);
    float ob0 = fmaxf(y0 * dvb + bias.x, 0.f);
    float ob1 = fmaxf(y1 * dvb + bias.y, 0.f);
    float ob2 = fmaxf(y2 * dvb + bias.z, 0.f);
    float ob3 = fmaxf(y3 * dvb + bias.w, 0.f);
    int g0 = __builtin_amdgcn_readfirstlane(ga);
    if (__all(ga == g0) && __all(gb == g0)) {      // ~98% of waves
        float f0 = oa0 + ob0, f1 = oa1 + ob1, f2 = oa2 + ob2, f3 = oa3 + ob3;
        f0 += __shfl_xor(f0, 16); f0 += __shfl_xor(f0, 32);
        f1 += __shfl_xor(f1, 16); f1 += __shfl_xor(f1, 32);
        f2 += __shfl_xor(f2, 16); f2 += __shfl_xor(f2, 32);
        f3 += __shfl_xor(f3, 16); f3 += __shfl_xor(f3, 32);
        if (sub == 0) {
            atomicAdd(&pooled[g0 * HID_C + 4 * c4 + 0], f0);
            atomicAdd(&pooled[g0 * HID_C + 4 * c4 + 1], f1);
            atomicAdd(&pooled[g0 * HID_C + 4 * c4 + 2], f2);
            atomicAdd(&pooled[g0 * HID_C + 4 * c4 + 3], f3);
        }
    } else {                                       // boundary wave: per-lane
        atomicAdd(&pooled[ga * HID_C + 4 * c4 + 0], oa0);
        atomicAdd(&pooled[ga * HID_C + 4 * c4 + 1], oa1);
        atomicAdd(&pooled[ga * HID_C + 4 * c4 + 2], oa2);
        atomicAdd(&pooled[ga * HID_C + 4 * c4 + 3], oa3);
        atomicAdd(&pooled[gb * HID_C + 4 * c4 + 0], ob0);
        atomicAdd(&pooled[gb * HID_C + 4 * c4 + 1], ob1);
        atomicAdd(&pooled[gb * HID_C + 4 * c4 + 2], ob2);
        atomicAdd(&pooled[gb * HID_C + 4 * c4 + 3], ob3);
    }
}

// ---- mean + FC; one block (64 thr) per graph (unchanged)
__global__ void k_fc(const float* __restrict__ pooled, const int* __restrict__ batch,
                     const float* __restrict__ Wfc, const float* __restrict__ bfc,
                     float* __restrict__ out) {
    int g = blockIdx.x;
    int c = threadIdx.x;
    int lo = 0, hi = N_NODES;
    while (lo < hi) { int mid = (lo + hi) >> 1; if (batch[mid] < g) lo = mid + 1; else hi = mid; }
    int start = lo;
    hi = N_NODES;
    while (lo < hi) { int mid = (lo + hi) >> 1; if (batch[mid] < g + 1) lo = mid + 1; else hi = mid; }
    int n = lo - start;
    float pv = pooled[g * HID_C + c] / (float)(n > 0 ? n : 1);
    float o0 = pv * Wfc[c * OUT_C + 0];
    float o1 = pv * Wfc[c * OUT_C + 1];
#pragma unroll
    for (int off = 32; off > 0; off >>= 1) {
        o0 += __shfl_down(o0, off);
        o1 += __shfl_down(o1, off);
    }
    if (c == 0) {
        out[g * OUT_C + 0] = o0 + bfc[0];
        out[g * OUT_C + 1] = o1 + bfc[1];
    }
}

extern "C" void kernel_launch(void* const* d_in, const int* in_sizes, int n_in,
                              void* d_out, int out_size, void* d_ws, size_t ws_size,
                              hipStream_t stream) {
    const float* x    = (const float*)d_in[0];
    const int*   ei   = (const int*)d_in[1];
    const int*   src  = ei;
    const int*   dst  = ei + N_EDGES;
    const int*   batch= (const int*)d_in[2];
    const float* W1   = (const float*)d_in[3];
    const float* b1   = (const float*)d_in[4];
    const float* W2   = (const float*)d_in[5];
    const float* b2   = (const float*)d_in[6];
    const float* Wfc  = (const float*)d_in[7];
    const float* bfc  = (const float*)d_in[8];
    float* out = (float*)d_out;

    // workspace layout (4B elems)
    float*  ws     = (float*)d_ws;
    float*  pooled = ws;                           // 16384 (zeroed by k_csort)
    float*  dinv   = ws + 16384;                   // 100352
    int*    cnt    = (int*)(dinv + 100352);        // 100352
    int*    rs     = cnt + 100352;                 // 100352
    int*    seg    = rs + 100352;                  // NCHUNK*SEGS = 459424
    int*    pairs  = seg + NCHUNK * SEGS;          // NCHUNK*EPB = 1200128 (chunk-major)
    int*    csr    = pairs + NCHUNK * EPB;         // NB*CAPB = 1601536 (bucket-major)
    float*  xs     = (float*)(csr + NB * CAPB);    // N*8 fp32 = 3.2 MB (16B-aligned)
    uint32* g2tab  = (uint32*)(xs + N_NODES * 8);  // N*32 uint32 = 12.8 MB

    // ---- CSR build: LDS chunk-sort (dense writes) + segment-gather bsort ----
    k_csort<<<NCHUNK, 256, 0, stream>>>(src, dst, pairs, seg, pooled);
    k_bsort_xs<<<NB, 256, 0, stream>>>(pairs, seg, x, csr, rs, cnt, dinv, xs);

    // ---- layer-1: 5-dim gather + @W1 + relu + @W2 (fused; weights in regs) ----
    {
        int blocks = (N_NODES + 4 * L1NPW - 1) / (4 * L1NPW);   // 3125
        k_l1<<<blocks, 256, 0, stream>>>(xs, csr, rs, cnt, dinv, b1, W1, W2, g2tab);
    }

    // ---- layer-2 gather + relu + mean-pool (v5: 2 nodes/lane, 16 in flight) ----
    {
        int waves = (N_NODES + GNPW - 1) / GNPW;     // 12500
        int blocks = (waves + 3) / 4;                // 3125
        k_gather2p<<<blocks, 256, 0, stream>>>(g2tab, csr, rs, cnt, dinv, b2, batch, pooled);
    }

    // ---- FC ----
    k_fc<<<N_GRAPHS, 64, 0, stream>>>(pooled, batch, Wfc, bfc, out);
}

// Round 15
// 188.114 us; speedup vs baseline: 1.1025x; 1.0144x over previous
//
#include <hip/hip_runtime.h>

#define N_NODES 100000
#define N_EDGES 1200000
#define N_GRAPHS 256
#define IN_C 5
#define HID_C 64
#define OUT_C 2

#define BSH 7
#define BNODES 128
#define NB ((N_NODES + BNODES - 1) / BNODES)        // 782
#define CAPB 2048                                   // fixed bucket capacity (E=1534, sigma=39)
#define EPB 2048                                    // edges per chunk
#define NCHUNK ((N_EDGES + EPB - 1) / EPB)          // 586
#define SEGS 784                                    // seg row stride (782 buckets + total + pad)
#define GNPW 8                                      // nodes per wave in fused gather2+pool
#define L1NPW 8                                     // nodes per wave in k_l1

typedef unsigned int uint32;

// fp32 -> bf16 round-to-nearest-even (returns 16-bit pattern)
__device__ __forceinline__ uint32 f2bf(float f) {
    uint32 x = __float_as_uint(f);
    return (x + 0x7FFFu + ((x >> 16) & 1u)) >> 16;
}
__device__ __forceinline__ float bflo(uint32 r) { return __uint_as_float(r << 16); }
__device__ __forceinline__ float bfhi(uint32 r) { return __uint_as_float(r & 0xFFFF0000u); }

// ---- chunk counting-sort: sort each 2048-edge chunk by bucket IN LDS, write
// sorted chunk DENSE (chunk-major pairs) + per-chunk segment offsets (seg).
// No global atomics, no scattered global writes. Blocks 0..63 also zero pooled.
__global__ void k_csort(const int* __restrict__ src, const int* __restrict__ dst,
                        int* __restrict__ pairs, int* __restrict__ seg,
                        float* __restrict__ pooled) {
    __shared__ int sp[EPB];          // 8 KB sorted payloads
    __shared__ int hist[782];
    __shared__ int st[256];
    int c = blockIdx.x, t = threadIdx.x;
    if (c < (N_GRAPHS * HID_C) / 256)
        pooled[c * 256 + t] = 0.f;
    for (int i = t; i < 782; i += 256) hist[i] = 0;
    __syncthreads();
    int e0 = c * EPB;
    int n = N_EDGES - e0; if (n > EPB) n = EPB;
    int pk[8], bk[8];
#pragma unroll
    for (int i = 0; i < 8; ++i) {
        int idx = t + i * 256;
        if (idx < n) {
            int d = dst[e0 + idx];
            bk[i] = d >> BSH;
            pk[i] = ((d & (BNODES - 1)) << 17) | src[e0 + idx];
            atomicAdd(&hist[bk[i]], 1);
        } else bk[i] = -1;
    }
    __syncthreads();
    // exclusive block-scan of hist[0..782), 4 elems/thread
    int i0 = t * 4;
    int v0 = (i0 + 0 < 782) ? hist[i0 + 0] : 0;
    int v1 = (i0 + 1 < 782) ? hist[i0 + 1] : 0;
    int v2 = (i0 + 2 < 782) ? hist[i0 + 2] : 0;
    int v3 = (i0 + 3 < 782) ? hist[i0 + 3] : 0;
    st[t] = v0 + v1 + v2 + v3;
    __syncthreads();
    for (int off = 1; off < 256; off <<= 1) {
        int a = (t >= off) ? st[t - off] : 0;
        __syncthreads();
        st[t] += a;
        __syncthreads();
    }
    int run = (t > 0) ? st[t - 1] : 0;
    if (i0 + 0 < 782) { hist[i0 + 0] = run; seg[c * SEGS + i0 + 0] = run; run += v0; }
    if (i0 + 1 < 782) { hist[i0 + 1] = run; seg[c * SEGS + i0 + 1] = run; run += v1; }
    if (i0 + 2 < 782) { hist[i0 + 2] = run; seg[c * SEGS + i0 + 2] = run; run += v2; }
    if (i0 + 3 < 782) { hist[i0 + 3] = run; seg[c * SEGS + i0 + 3] = run; run += v3; }
    if (t == 0) seg[c * SEGS + 782] = n;
    __syncthreads();
    // placement into LDS (hist doubles as cursor)
#pragma unroll
    for (int i = 0; i < 8; ++i)
        if (bk[i] >= 0) {
            int pos = atomicAdd(&hist[bk[i]], 1);
            sp[pos] = pk[i];
        }
    __syncthreads();
    for (int i = t; i < n; i += 256)
        pairs[c * EPB + i] = sp[i];      // dense coalesced write-out
}

// ---- per-bucket counting sort -> CSR + rs/cnt/dinv + xs epilogue.
// v4: phase C gather via BINARY SEARCH -> each edge-slot is an independent
// scattered read (r14 lesson: v3's per-thread serial segment walk chained
// ~6 dependent ~400cy loads; now all slots issue in parallel).
__global__ void k_bsort_xs(const int* __restrict__ pairs, const int* __restrict__ seg,
                           const float* __restrict__ x,
                           int* __restrict__ csr, int* __restrict__ rs,
                           int* __restrict__ cnt, float* __restrict__ dinv,
                           float* __restrict__ xs) {
    __shared__ int spairs[CAPB];        // 8 KB
    __shared__ int ssorted[CAPB];       // 8 KB
    __shared__ int ssrc[NCHUNK];        // 2.3 KB (global index of segment start)
    __shared__ int sdst[NCHUNK];        // 2.3 KB (dst offset in spairs)
    __shared__ int st[256];
    __shared__ int hist[BNODES];
    __shared__ int tmp[BNODES];
    __shared__ int cur[BNODES];
    __shared__ float sdv[BNODES];
    int b = blockIdx.x;
    int t = threadIdx.x;
    int base = b << BSH;
    // A: per-chunk segment bounds for this bucket (slen kept in registers via st)
    for (int c = t; c < NCHUNK; c += 256) {
        int s0 = seg[c * SEGS + b];
        int s1 = seg[c * SEGS + b + 1];
        sdst[c] = s1 - s0;              // temporarily holds length
        ssrc[c] = c * EPB + s0;
    }
    if (t < BNODES) hist[t] = 0;
    __syncthreads();
    // B: exclusive scan of lengths (4 elems/thread) -> sdst = start offsets
    int i0 = t * 4;
    int v0 = (i0 + 0 < NCHUNK) ? sdst[i0 + 0] : 0;
    int v1 = (i0 + 1 < NCHUNK) ? sdst[i0 + 1] : 0;
    int v2 = (i0 + 2 < NCHUNK) ? sdst[i0 + 2] : 0;
    int v3 = (i0 + 3 < NCHUNK) ? sdst[i0 + 3] : 0;
    st[t] = v0 + v1 + v2 + v3;
    __syncthreads();
    for (int off = 1; off < 256; off <<= 1) {
        int a = (t >= off) ? st[t - off] : 0;
        __syncthreads();
        st[t] += a;
        __syncthreads();
    }
    int run = (t > 0) ? st[t - 1] : 0;
    __syncthreads();                    // all reads of old sdst done
    if (i0 + 0 < NCHUNK) { sdst[i0 + 0] = run; run += v0; }
    if (i0 + 1 < NCHUNK) { sdst[i0 + 1] = run; run += v1; }
    if (i0 + 2 < NCHUNK) { sdst[i0 + 2] = run; run += v2; }
    if (i0 + 3 < NCHUNK) { sdst[i0 + 3] = run; run += v3; }
    __syncthreads();
    int n = st[255];                    // bucket total
    if (n > CAPB) n = CAPB;             // safety clamp (13-sigma headroom)
    // C: parallel gather: slot i -> chunk via binary search (independent loads)
    for (int i = t; i < n; i += 256) {
        int lo = 0, hi = NCHUNK - 1;
        while (lo < hi) {               // largest c with sdst[c] <= i
            int mid = (lo + hi + 1) >> 1;
            if (sdst[mid] <= i) lo = mid; else hi = mid - 1;
        }
        int p = pairs[ssrc[lo] + (i - sdst[lo])];
        spairs[i] = p;
        atomicAdd(&hist[p >> 17], 1);
    }
    __syncthreads();
    // D: per-node counting sort (proven v2 path)
    int v = (t < BNODES) ? hist[t] : 0;
    if (t < BNODES) tmp[t] = v;
    __syncthreads();
    for (int off = 1; off < BNODES; off <<= 1) {
        int a = (t < BNODES && t >= off) ? tmp[t - off] : 0;
        __syncthreads();
        if (t < BNODES) tmp[t] += a;
        __syncthreads();
    }
    float dv_t = rsqrtf((float)v + 1.0f);
    int s = b << 11;                    // fixed bucket start in csr
    if (t < BNODES) {
        cur[t] = tmp[t] - v;
        sdv[t] = dv_t;
        if (base + t < N_NODES) {
            rs[base + t] = s + tmp[t] - v;
            cnt[base + t] = v;
            dinv[base + t] = dv_t;
        }
    }
    __syncthreads();
    for (int i = t; i < n; i += 256) {
        int p = spairs[i];
        int pos = atomicAdd(&cur[p >> 17], 1);
        ssorted[pos] = p & 0x1FFFF;
    }
    __syncthreads();
    for (int i = t; i < n; i += 256)
        csr[s + i] = ssorted[i];        // dense coalesced write-out
    // ---- xs epilogue: xs[node*8+k] = x[node*5+k] * dinv[node], k<5 ----
    for (int i = t; i < BNODES * 8; i += 256) {
        int nl = i >> 3, k = i & 7;
        int node = base + nl;
        if (node < N_NODES && k < IN_C)
            xs[(unsigned)node * 8 + k] = x[(unsigned)node * IN_C + k] * sdv[nl];
    }
}

// ---- fused layer-1: 5-dim gather (L2-resident xs table) + @W1 + relu + @W2,
// writes g2tab (bf16x2 packed). W1/W2 columns live in REGISTERS (each lane
// owns a fixed channel pair), h-row bounces through LDS as broadcast b128 reads.
__global__ void __launch_bounds__(256) k_l1(
        const float* __restrict__ xs, const int* __restrict__ csr,
        const int* __restrict__ rs, const int* __restrict__ cnt,
        const float* __restrict__ dinv, const float* __restrict__ b1,
        const float* __restrict__ W1, const float* __restrict__ W2,
        uint32* __restrict__ g2t) {
    __shared__ __align__(16) float sagg[4][L1NPW][8];   // 1 KB
    __shared__ __align__(16) float srow[4][2][HID_C];   // 2 KB
    int tid = threadIdx.x;
    int w = tid >> 6;
    int lane = tid & 63;
    int base = (blockIdx.x * 4 + w) * L1NPW;

    // ---- gather phase: 8 lanes per node, fp32 5-vec accumulate (pipelined) ----
    int g = lane >> 3, l = lane & 7;
    int v = base + g;
    float a0 = 0.f, a1 = 0.f, a2 = 0.f, a3 = 0.f, a4 = 0.f;
    if (v < N_NODES) {
        int k0 = rs[v];
        int n = cnt[v];
        if (l == 0) {           // self-loop contribution
            float4 p = *(const float4*)&xs[(unsigned)v * 8];
            a0 = p.x; a1 = p.y; a2 = p.z; a3 = p.w;
            a4 = xs[(unsigned)v * 8 + 4];
        }
        int i = l;
        int un = (i < n) ? csr[k0 + i] : -1;
        while (un >= 0) {
            int u = un;
            i += 8;
            un = (i < n) ? csr[k0 + i] : -1;   // next csr overlaps this xs gather
            float4 p = *(const float4*)&xs[(unsigned)u * 8];
            float p4 = xs[(unsigned)u * 8 + 4];
            a0 += p.x; a1 += p.y; a2 += p.z; a3 += p.w; a4 += p4;
        }
    }
#pragma unroll
    for (int off = 4; off; off >>= 1) {
        a0 += __shfl_xor(a0, off);
        a1 += __shfl_xor(a1, off);
        a2 += __shfl_xor(a2, off);
        a3 += __shfl_xor(a3, off);
        a4 += __shfl_xor(a4, off);
    }
    if (l == 0 && v < N_NODES) {
        *(float4*)&sagg[w][g][0] = make_float4(a0, a1, a2, a3);
        sagg[w][g][4] = a4;
    }

    // ---- weight columns -> registers (static indexing only) ----
    int half = lane >> 5, c2 = lane & 31;
    int kb = half << 5;
    float2 w1r[IN_C];
#pragma unroll
    for (int k = 0; k < IN_C; ++k)
        w1r[k] = *(const float2*)&W1[k * HID_C + 2 * c2];
    float2 w2r[32];
#pragma unroll
    for (int j = 0; j < 32; ++j)
        w2r[j] = *(const float2*)&W2[(kb + j) * HID_C + 2 * c2];
    float2 bias = *(const float2*)&b1[2 * c2];

    // ---- dense phase: h1 = relu(dinv*(agg@W1)+b1); g2 = bf16(dinv*(h1@W2)) ----
    for (int gg = 0; gg < L1NPW; ++gg) {
        int node = base + gg;                 // base wave-uniform -> uniform break
        if (node >= N_NODES) break;
        float dv = dinv[node];
        float4 qa = *(const float4*)&sagg[w][gg][0];
        float q4 = sagg[w][gg][4];
        float s0 = qa.x * w1r[0].x + qa.y * w1r[1].x + qa.z * w1r[2].x
                 + qa.w * w1r[3].x + q4 * w1r[4].x;
        float s1 = qa.x * w1r[0].y + qa.y * w1r[1].y + qa.z * w1r[2].y
                 + qa.w * w1r[3].y + q4 * w1r[4].y;
        float h0 = fmaxf(s0 * dv + bias.x, 0.f);
        float h1 = fmaxf(s1 * dv + bias.y, 0.f);
        int buf = gg & 1;
        if (half == 0) *(float2*)&srow[w][buf][2 * c2] = make_float2(h0, h1);
        float t0 = 0.f, t1 = 0.f;
#pragma unroll
        for (int jj = 0; jj < 8; ++jj) {
            float4 hv = *(const float4*)&srow[w][buf][kb + 4 * jj];  // broadcast
            t0 += hv.x * w2r[4 * jj + 0].x + hv.y * w2r[4 * jj + 1].x
                + hv.z * w2r[4 * jj + 2].x + hv.w * w2r[4 * jj + 3].x;
            t1 += hv.x * w2r[4 * jj + 0].y + hv.y * w2r[4 * jj + 1].y
                + hv.z * w2r[4 * jj + 2].y + hv.w * w2r[4 * jj + 3].y;
        }
        t0 += __shfl_xor(t0, 32);
        t1 += __shfl_xor(t1, 32);
        if (half == 0)
            g2t[(unsigned)node * 32 + c2] = (f2bf(t1 * dv) << 16) | f2bf(t0 * dv);
    }
}

// ---- gather layer 2 fused with relu + mean-pool accumulate (v5).
// Each lane owns TWO nodes (va = n0+sub, vb = n0+4+sub), fused body with
// 8+8 = 16 independent gathers in flight; uniform-wave shuffle-merged flush.
#define LDU2(d, u) uint2 d = *(const uint2*)&g[(unsigned)(u) * 32 + 2 * c4]
#define ACC4(s0, s1, s2, s3, r) { s0 += bflo(r.x); s1 += bfhi(r.x); \
                                  s2 += bflo(r.y); s3 += bfhi(r.y); }
__global__ void __launch_bounds__(256, 4) k_gather2p(
        const uint32* __restrict__ g, const int* __restrict__ csr,
        const int* __restrict__ rs, const int* __restrict__ cnt,
        const float* __restrict__ dinv, const float* __restrict__ b,
        const int* __restrict__ batch, float* __restrict__ pooled) {
    int wv = __builtin_amdgcn_readfirstlane(
        blockIdx.x * (blockDim.x >> 6) + (threadIdx.x >> 6));
    int n0 = wv * GNPW;
    if (n0 >= N_NODES) return;            // grid exact: 12500*8 == N_NODES
    int lane = threadIdx.x & 63;
    int sub = lane >> 4;                  // node slot (0..3)
    int c4 = lane & 15;                   // channel-quad index
    int va = n0 + sub, vb = n0 + 4 + sub;
    int ka = rs[va], na = cnt[va];
    int kb = rs[vb], nb = cnt[vb];
    float dva = dinv[va], dvb = dinv[vb];
    int ga = batch[va], gb = batch[vb];
    float4 bias = *(const float4*)&b[4 * c4];
    LDU2(rsa, va); LDU2(rsb, vb);         // self-loops
    float a0 = bflo(rsa.x), a1 = bfhi(rsa.x), a2 = bflo(rsa.y), a3 = bfhi(rsa.y);
    float y0 = bflo(rsb.x), y1 = bfhi(rsb.x), y2 = bflo(rsb.y), y3 = bfhi(rsb.y);
    int ia = 0, ib = 0;
    while (ia + 7 < na && ib + 7 < nb) {
        int u0 = csr[ka+ia+0], u1 = csr[ka+ia+1], u2 = csr[ka+ia+2], u3 = csr[ka+ia+3];
        int u4 = csr[ka+ia+4], u5 = csr[ka+ia+5], u6 = csr[ka+ia+6], u7 = csr[ka+ia+7];
        int w0 = csr[kb+ib+0], w1 = csr[kb+ib+1], w2 = csr[kb+ib+2], w3 = csr[kb+ib+3];
        int w4 = csr[kb+ib+4], w5 = csr[kb+ib+5], w6 = csr[kb+ib+6], w7 = csr[kb+ib+7];
        LDU2(p0, u0); LDU2(p1, u1); LDU2(p2, u2); LDU2(p3, u3);
        LDU2(p4, u4); LDU2(p5, u5); LDU2(p6, u6); LDU2(p7, u7);
        LDU2(q0, w0); LDU2(q1, w1); LDU2(q2, w2); LDU2(q3, w3);
        LDU2(q4, w4); LDU2(q5, w5); LDU2(q6, w6); LDU2(q7, w7);
        ACC4(a0, a1, a2, a3, p0); ACC4(a0, a1, a2, a3, p1);
        ACC4(a0, a1, a2, a3, p2); ACC4(a0, a1, a2, a3, p3);
        ACC4(a0, a1, a2, a3, p4); ACC4(a0, a1, a2, a3, p5);
        ACC4(a0, a1, a2, a3, p6); ACC4(a0, a1, a2, a3, p7);
        ACC4(y0, y1, y2, y3, q0); ACC4(y0, y1, y2, y3, q1);
        ACC4(y0, y1, y2, y3, q2); ACC4(y0, y1, y2, y3, q3);
        ACC4(y0, y1, y2, y3, q4); ACC4(y0, y1, y2, y3, q5);
        ACC4(y0, y1, y2, y3, q6); ACC4(y0, y1, y2, y3, q7);
        ia += 8; ib += 8;
    }
    while (ia + 7 < na) {
        int u0 = csr[ka+ia+0], u1 = csr[ka+ia+1], u2 = csr[ka+ia+2], u3 = csr[ka+ia+3];
        int u4 = csr[ka+ia+4], u5 = csr[ka+ia+5], u6 = csr[ka+ia+6], u7 = csr[ka+ia+7];
        LDU2(p0, u0); LDU2(p1, u1); LDU2(p2, u2); LDU2(p3, u3);
        LDU2(p4, u4); LDU2(p5, u5); LDU2(p6, u6); LDU2(p7, u7);
        ACC4(a0, a1, a2, a3, p0); ACC4(a0, a1, a2, a3, p1);
        ACC4(a0, a1, a2, a3, p2); ACC4(a0, a1, a2, a3, p3);
        ACC4(a0, a1, a2, a3, p4); ACC4(a0, a1, a2, a3, p5);
        ACC4(a0, a1, a2, a3, p6); ACC4(a0, a1, a2, a3, p7);
        ia += 8;
    }
    while (ib + 7 < nb) {
        int w0 = csr[kb+ib+0], w1 = csr[kb+ib+1], w2 = csr[kb+ib+2], w3 = csr[kb+ib+3];
        int w4 = csr[kb+ib+4], w5 = csr[kb+ib+5], w6 = csr[kb+ib+6], w7 = csr[kb+ib+7];
        LDU2(q0, w0); LDU2(q1, w1); LDU2(q2, w2); LDU2(q3, w3);
        LDU2(q4, w4); LDU2(q5, w5); LDU2(q6, w6); LDU2(q7, w7);
        ACC4(y0, y1, y2, y3, q0); ACC4(y0, y1, y2, y3, q1);
        ACC4(y0, y1, y2, y3, q2); ACC4(y0, y1, y2, y3, q3);
        ACC4(y0, y1, y2, y3, q4); ACC4(y0, y1, y2, y3, q5);
        ACC4(y0, y1, y2, y3, q6); ACC4(y0, y1, y2, y3, q7);
        ib += 8;
    }
    while (ia + 3 < na && ib + 3 < nb) {
        int u0 = csr[ka+ia+0], u1 = csr[ka+ia+1], u2 = csr[ka+ia+2], u3 = csr[ka+ia+3];
        int w0 = csr[kb+ib+0], w1 = csr[kb+ib+1], w2 = csr[kb+ib+2], w3 = csr[kb+ib+3];
        LDU2(p0, u0); LDU2(p1, u1); LDU2(p2, u2); LDU2(p3, u3);
        LDU2(q0, w0); LDU2(q1, w1); LDU2(q2, w2); LDU2(q3, w3);
        ACC4(a0, a1, a2, a3, p0); ACC4(a0, a1, a2, a3, p1);
        ACC4(a0, a1, a2, a3, p2); ACC4(a0, a1, a2, a3, p3);
        ACC4(y0, y1, y2, y3, q0); ACC4(y0, y1, y2, y3, q1);
        ACC4(y0, y1, y2, y3, q2); ACC4(y0, y1, y2, y3, q3);
        ia += 4; ib += 4;
    }
    while (ia + 3 < na) {
        int u0 = csr[ka+ia+0], u1 = csr[ka+ia+1], u2 = csr[ka+ia+2], u3 = csr[ka+ia+3];
        LDU2(p0, u0); LDU2(p1, u1); LDU2(p2, u2); LDU2(p3, u3);
        ACC4(a0, a1, a2, a3, p0); ACC4(a0, a1, a2, a3, p1);
        ACC4(a0, a1, a2, a3, p2); ACC4(a0, a1, a2, a3, p3);
        ia += 4;
    }
    while (ib + 3 < nb) {
        int w0 = csr[kb+ib+0], w1 = csr[kb+ib+1], w2 = csr[kb+ib+2], w3 = csr[kb+ib+3];
        LDU2(q0, w0); LDU2(q1, w1); LDU2(q2, w2); LDU2(q3, w3);
        ACC4(y0, y1, y2, y3, q0); ACC4(y0, y1, y2, y3, q1);
        ACC4(y0, y1, y2, y3, q2); ACC4(y0, y1, y2, y3, q3);
        ib += 4;
    }
    while (ia < na && ib < nb) {
        int u0 = csr[ka + ia], w0 = csr[kb + ib];
        LDU2(p0, u0); LDU2(q0, w0);
        ACC4(a0, a1, a2, a3, p0); ACC4(y0, y1, y2, y3, q0);
        ++ia; ++ib;
    }
    while (ia < na) {
        LDU2(p0, csr[ka + ia]);
        ACC4(a0, a1, a2, a3, p0);
        ++ia;
    }
    while (ib < nb) {
        LDU2(q0, csr[kb + ib]);
        ACC4(y0, y1, y2, y3, q0);
        ++ib;
    }
    float oa0 = fmaxf(a0 * dva + bias.x, 0.f);
    float oa1 = fmaxf(a1 * dva + bias.y, 0.f);
    float oa2 = fmaxf(a2 * dva + bias.z, 0.f);
    float oa3 = fmaxf(a3 * dva + bias.w, 0.f);
    float ob0 = fmaxf(y0 * dvb + bias.x, 0.f);
    float ob1 = fmaxf(y1 * dvb + bias.y, 0.f);
    float ob2 = fmaxf(y2 * dvb + bias.z, 0.f);
    float ob3 = fmaxf(y3 * dvb + bias.w, 0.f);
    int g0 = __builtin_amdgcn_readfirstlane(ga);
    if (__all(ga == g0) && __all(gb == g0)) {      // ~98% of waves
        float f0 = oa0 + ob0, f1 = oa1 + ob1, f2 = oa2 + ob2, f3 = oa3 + ob3;
        f0 += __shfl_xor(f0, 16); f0 += __shfl_xor(f0, 32);
        f1 += __shfl_xor(f1, 16); f1 += __shfl_xor(f1, 32);
        f2 += __shfl_xor(f2, 16); f2 += __shfl_xor(f2, 32);
        f3 += __shfl_xor(f3, 16); f3 += __shfl_xor(f3, 32);
        if (sub == 0) {
            atomicAdd(&pooled[g0 * HID_C + 4 * c4 + 0], f0);
            atomicAdd(&pooled[g0 * HID_C + 4 * c4 + 1], f1);
            atomicAdd(&pooled[g0 * HID_C + 4 * c4 + 2], f2);
            atomicAdd(&pooled[g0 * HID_C + 4 * c4 + 3], f3);
        }
    } else {                                       // boundary wave: per-lane
        atomicAdd(&pooled[ga * HID_C + 4 * c4 + 0], oa0);
        atomicAdd(&pooled[ga * HID_C + 4 * c4 + 1], oa1);
        atomicAdd(&pooled[ga * HID_C + 4 * c4 + 2], oa2);
        atomicAdd(&pooled[ga * HID_C + 4 * c4 + 3], oa3);
        atomicAdd(&pooled[gb * HID_C + 4 * c4 + 0], ob0);
        atomicAdd(&pooled[gb * HID_C + 4 * c4 + 1], ob1);
        atomicAdd(&pooled[gb * HID_C + 4 * c4 + 2], ob2);
        atomicAdd(&pooled[gb * HID_C + 4 * c4 + 3], ob3);
    }
}

// ---- mean + FC; one block (64 thr) per graph (unchanged)
__global__ void k_fc(const float* __restrict__ pooled, const int* __restrict__ batch,
                     const float* __restrict__ Wfc, const float* __restrict__ bfc,
                     float* __restrict__ out) {
    int g = blockIdx.x;
    int c = threadIdx.x;
    int lo = 0, hi = N_NODES;
    while (lo < hi) { int mid = (lo + hi) >> 1; if (batch[mid] < g) lo = mid + 1; else hi = mid; }
    int start = lo;
    hi = N_NODES;
    while (lo < hi) { int mid = (lo + hi) >> 1; if (batch[mid] < g + 1) lo = mid + 1; else hi = mid; }
    int n = lo - start;
    float pv = pooled[g * HID_C + c] / (float)(n > 0 ? n : 1);
    float o0 = pv * Wfc[c * OUT_C + 0];
    float o1 = pv * Wfc[c * OUT_C + 1];
#pragma unroll
    for (int off = 32; off > 0; off >>= 1) {
        o0 += __shfl_down(o0, off);
        o1 += __shfl_down(o1, off);
    }
    if (c == 0) {
        out[g * OUT_C + 0] = o0 + bfc[0];
        out[g * OUT_C + 1] = o1 + bfc[1];
    }
}

extern "C" void kernel_launch(void* const* d_in, const int* in_sizes, int n_in,
                              void* d_out, int out_size, void* d_ws, size_t ws_size,
                              hipStream_t stream) {
    const float* x    = (const float*)d_in[0];
    const int*   ei   = (const int*)d_in[1];
    const int*   src  = ei;
    const int*   dst  = ei + N_EDGES;
    const int*   batch= (const int*)d_in[2];
    const float* W1   = (const float*)d_in[3];
    const float* b1   = (const float*)d_in[4];
    const float* W2   = (const float*)d_in[5];
    const float* b2   = (const float*)d_in[6];
    const float* Wfc  = (const float*)d_in[7];
    const float* bfc  = (const float*)d_in[8];
    float* out = (float*)d_out;

    // workspace layout (4B elems)
    float*  ws     = (float*)d_ws;
    float*  pooled = ws;                           // 16384 (zeroed by k_csort)
    float*  dinv   = ws + 16384;                   // 100352
    int*    cnt    = (int*)(dinv + 100352);        // 100352
    int*    rs     = cnt + 100352;                 // 100352
    int*    seg    = rs + 100352;                  // NCHUNK*SEGS = 459424
    int*    pairs  = seg + NCHUNK * SEGS;          // NCHUNK*EPB = 1200128 (chunk-major)
    int*    csr    = pairs + NCHUNK * EPB;         // NB*CAPB = 1601536 (bucket-major)
    float*  xs     = (float*)(csr + NB * CAPB);    // N*8 fp32 = 3.2 MB (16B-aligned)
    uint32* g2tab  = (uint32*)(xs + N_NODES * 8);  // N*32 uint32 = 12.8 MB

    // ---- CSR build: LDS chunk-sort (dense writes) + binary-search bsort ----
    k_csort<<<NCHUNK, 256, 0, stream>>>(src, dst, pairs, seg, pooled);
    k_bsort_xs<<<NB, 256, 0, stream>>>(pairs, seg, x, csr, rs, cnt, dinv, xs);

    // ---- layer-1: 5-dim gather + @W1 + relu + @W2 (fused; weights in regs) ----
    {
        int blocks = (N_NODES + 4 * L1NPW - 1) / (4 * L1NPW);   // 3125
        k_l1<<<blocks, 256, 0, stream>>>(xs, csr, rs, cnt, dinv, b1, W1, W2, g2tab);
    }

    // ---- layer-2 gather + relu + mean-pool (v5: 2 nodes/lane, 16 in flight) ----
    {
        int waves = (N_NODES + GNPW - 1) / GNPW;     // 12500
        int blocks = (waves + 3) / 4;                // 3125
        k_gather2p<<<blocks, 256, 0, stream>>>(g2tab, csr, rs, cnt, dinv, b2, batch, pooled);
    }

    // ---- FC ----
    k_fc<<<N_GRAPHS, 64, 0, stream>>>(pooled, batch, Wfc, bfc, out);
}